// Round 7
// baseline (216.790 us; speedup 1.0000x reference)
//
#include <hip/hip_runtime.h>
#include <hip/hip_bf16.h>
#include <math.h>

#define CCLS 16
#define BB   2048
#define NBT  32   // BB / 64 b-tiles (all layers)

using bf16x8 = __attribute__((ext_vector_type(8))) short;
using short8 = __attribute__((ext_vector_type(8))) short;
using f32x4  = __attribute__((ext_vector_type(4))) float;

// fp32 -> (hi, lo) bf16 split (RNE; hi+lo reproduces ~24 mantissa bits)
__device__ __forceinline__ void split2(float e, short& hi, short& lo) {
    __hip_bfloat16 h = __float2bfloat16(e);
    hi = __builtin_bit_cast(short, h);
    lo = __builtin_bit_cast(short, __float2bfloat16(e - __bfloat162float(h)));
}

// LDS-visibility barrier that does NOT drain vmcnt: global loads stay in
// flight across it (compiler inserts counted vmcnt(N) before each use).
__device__ __forceinline__ void soft_barrier() {
    asm volatile("s_waitcnt lgkmcnt(0)" ::: "memory");
    __builtin_amdgcn_s_barrier();
    asm volatile("" ::: "memory");
}

// Fragment-major layout for a 64-row x 32-k bf16 tile (4 KB/plane):
//   L(row, kchunk) = (row>>4)<<10 | kchunk<<8 | (row&15)<<4   (kchunk = k/8)
// A 16-lane frag read covers 256B contiguous -> conflict-free.

// ---------------------------------------------------------------------------
// One-time W pack: W1..W5 -> [hi 4KB][lo 4KB] fragment-major 64x32 tiles,
// tile order per source: (c, otile, ks). Zero-padded past kreal.
// ---------------------------------------------------------------------------
struct PackDesc {
    const float* src[5];
    int ot[5];      // Fout/64
    int ksn[5];     // ceil(K/32)
    int kreal[5];
    int beg[6];     // tile-range starts
};

__global__ __launch_bounds__(256)
void pack_kernel(PackDesc d, char* __restrict__ base)
{
    const int bid = blockIdx.x;
    int s = 0;
    #pragma unroll
    for (int i = 0; i < 4; ++i) s += (bid >= d.beg[i + 1]);
    const int t    = bid - d.beg[s];
    const int ksn  = d.ksn[s], OT = d.ot[s], kreal = d.kreal[s];
    const int per  = OT * ksn;
    const int c  = t / per;
    const int r  = t - c * per;
    const int o  = r / ksn;
    const int ks = r - o * ksn;
    const float* src = d.src[s] + ((size_t)(c * OT + o) * 64) * kreal;
    char* dst = base + (size_t)bid * 8192;

    const int tid  = threadIdx.x;
    const int row  = tid >> 2, asub = tid & 3;
    const int q    = ((row >> 4) << 10) | (asub << 8) | ((row & 15) << 4);
    const int k0   = ks * 32 + asub * 8;
    const float* sp = src + (size_t)row * kreal + k0;

    float e[8];
    if (k0 + 8 <= kreal) {
        float4 v0 = *(const float4*)sp;
        float4 v1 = *(const float4*)(sp + 4);
        e[0]=v0.x; e[1]=v0.y; e[2]=v0.z; e[3]=v0.w;
        e[4]=v1.x; e[5]=v1.y; e[6]=v1.z; e[7]=v1.w;
    } else {
        #pragma unroll
        for (int j = 0; j < 8; ++j) e[j] = (k0 + j < kreal) ? sp[j] : 0.f;
    }
    short hv[8], lv[8];
    #pragma unroll
    for (int j = 0; j < 8; ++j) split2(e[j], hv[j], lv[j]);
    *(short8*)(dst + q)        = (short8){hv[0],hv[1],hv[2],hv[3],hv[4],hv[5],hv[6],hv[7]};
    *(short8*)(dst + 4096 + q) = (short8){lv[0],lv[1],lv[2],lv[3],lv[4],lv[5],lv[6],lv[7]};
}

// ---------------------------------------------------------------------------
// MFMA GEMM, fp32 via bf16 hi/lo 3-product emulation. TLP-first design:
// 64x64x32 tile, 4 waves (2x2, each 32x32 = 2x2 frags x3 MFMA), grids of
// 1024-4096 blocks so block churn hides latency. A (fp32) reg-staged ->
// [BN+ReLU] -> hi/lo bf16 in LDS (dbuf, 1 soft barrier/step, vmcnt never
// drained). W fragments global->VGPR, register-dbuf one step ahead.
// BN scale/shift of the INPUT computed in-prologue from producer's partial
// stats; deterministic partial stats of the OUTPUT per (c, feature, btile).
// ---------------------------------------------------------------------------
template<int K, bool FUSE_BN, bool WRITE_STATS>
__global__ __launch_bounds__(256, 4)
void gemm6_kernel(const float* __restrict__ A, const char* __restrict__ Wpk,
                  const float* __restrict__ bias,
                  const float* __restrict__ psumIn, const float* __restrict__ psqIn,
                  const float* __restrict__ gIn, const float* __restrict__ beIn,
                  float* __restrict__ Out,
                  float* __restrict__ psumOut, float* __restrict__ psqOut,
                  const int Fout)
{
    constexpr int KS    = (K + 31) / 32;
    constexpr int PLANE = 4096;
    constexpr int BUF   = 8192;          // hi+lo pair

    __shared__ __align__(16) char sm[2 * BUF + (FUSE_BN ? 8 * K : 16)];
    float* scs = (float*)(sm + 2 * BUF);
    float* shs = scs + (FUSE_BN ? K : 0);

    const int tid = threadIdx.x;
    const int bx  = blockIdx.x;
    // XCD-cluster swizzle (gx=32): XCD k gets btiles 4k..4k+3 -> W panels and
    // BN-stat slices stay L2-local within an XCD's contiguous run.
    const int btile = ((bx & 7) << 2) | (bx >> 3);
    const int otile = blockIdx.y, c = blockIdx.z;

    // ---- folded combine: BN scale/shift for this layer's INPUT features ----
    if (FUSE_BN) {
        for (int f = tid; f < K; f += 256) {
            const float* ps = psumIn + ((size_t)c * K + f) * NBT;
            const float* pq = psqIn  + ((size_t)c * K + f) * NBT;
            float s = 0.f, q = 0.f;
            #pragma unroll
            for (int t = 0; t < NBT; t += 4) {
                float4 a4 = *(const float4*)(ps + t);
                float4 b4 = *(const float4*)(pq + t);
                s += (a4.x + a4.y) + (a4.z + a4.w);
                q += (b4.x + b4.y) + (b4.z + b4.w);
            }
            const float mean = s * (1.f / BB);
            const float var  = q * (1.f / BB) - mean * mean;
            const float rstd = rsqrtf(var + 1e-5f);
            const float scv  = gIn[(size_t)c * K + f] * rstd;
            scs[f] = scv;
            shs[f] = fmaf(-mean, scv, beIn[(size_t)c * K + f]);
        }
        __syncthreads();
    }

    const int b0 = btile * 64, o0 = otile * 64;
    const int OT = Fout >> 6;
    const char* wbase = Wpk + (size_t)((c * OT + otile) * KS) * 8192;

    // A staging map: 4 threads per row, 8 floats each
    const int arow = tid >> 2, asub = tid & 3;
    const int ak0  = asub << 3;
    const int awr  = ((arow >> 4) << 10) | (asub << 8) | ((arow & 15) << 4);
    const float* Arow = A + ((size_t)c * BB + b0 + arow) * K;

    // fragment map: 4 waves 2x2, each 32x32
    const int lane = tid & 63, wv = tid >> 6;
    const int fr = lane & 15, fkc = lane >> 4;
    const int wrow = (wv >> 1) << 5, wcol = (wv & 1) << 5;
    const int wrg = wrow >> 4, wcg = wcol >> 4;

    auto loadA = [&](float* e, int gk0) {
        if constexpr ((K & 31) != 0) {
            if (gk0 + 8 <= K) {
                float4 v0 = *(const float4*)(Arow + gk0);
                float4 v1 = *(const float4*)(Arow + gk0 + 4);
                e[0]=v0.x; e[1]=v0.y; e[2]=v0.z; e[3]=v0.w;
                e[4]=v1.x; e[5]=v1.y; e[6]=v1.z; e[7]=v1.w;
            } else {
                #pragma unroll
                for (int j = 0; j < 8; ++j) e[j] = (gk0 + j < K) ? Arow[gk0 + j] : 0.f;
            }
        } else {
            float4 v0 = *(const float4*)(Arow + gk0);
            float4 v1 = *(const float4*)(Arow + gk0 + 4);
            e[0]=v0.x; e[1]=v0.y; e[2]=v0.z; e[3]=v0.w;
            e[4]=v1.x; e[5]=v1.y; e[6]=v1.z; e[7]=v1.w;
        }
    };
    auto loadW = [&](bf16x8* w, int ks) {
        const char* wt = wbase + (size_t)ks * 8192;
        #pragma unroll
        for (int i = 0; i < 2; ++i) {
            const int wo = ((wcg + i) << 10) | (fkc << 8) | (fr << 4);
            w[i]     = *(const bf16x8*)(wt + wo);          // hi
            w[2 + i] = *(const bf16x8*)(wt + 4096 + wo);   // lo
        }
    };
    auto cvtStore = [&](char* dstbase, const float* ein, int gk0) {
        float e[8];
        #pragma unroll
        for (int j = 0; j < 8; ++j) e[j] = ein[j];
        if constexpr (FUSE_BN) {
            const float4 sc0 = *(const float4*)(scs + gk0);
            const float4 sc1 = *(const float4*)(scs + gk0 + 4);
            const float4 sh0 = *(const float4*)(shs + gk0);
            const float4 sh1 = *(const float4*)(shs + gk0 + 4);
            e[0] = fmaxf(0.f, fmaf(e[0], sc0.x, sh0.x));
            e[1] = fmaxf(0.f, fmaf(e[1], sc0.y, sh0.y));
            e[2] = fmaxf(0.f, fmaf(e[2], sc0.z, sh0.z));
            e[3] = fmaxf(0.f, fmaf(e[3], sc0.w, sh0.w));
            e[4] = fmaxf(0.f, fmaf(e[4], sc1.x, sh1.x));
            e[5] = fmaxf(0.f, fmaf(e[5], sc1.y, sh1.y));
            e[6] = fmaxf(0.f, fmaf(e[6], sc1.z, sh1.z));
            e[7] = fmaxf(0.f, fmaf(e[7], sc1.w, sh1.w));
        }
        short h[8], l[8];
        #pragma unroll
        for (int j = 0; j < 8; ++j) split2(e[j], h[j], l[j]);
        *(short8*)(dstbase + awr)         = (short8){h[0],h[1],h[2],h[3],h[4],h[5],h[6],h[7]};
        *(short8*)(dstbase + PLANE + awr) = (short8){l[0],l[1],l[2],l[3],l[4],l[5],l[6],l[7]};
    };

    f32x4 acc[2][2];
    #pragma unroll
    for (int mi = 0; mi < 2; ++mi)
        #pragma unroll
        for (int ni = 0; ni < 2; ++ni)
            acc[mi][ni] = (f32x4){0.f, 0.f, 0.f, 0.f};

    bf16x8 wc[4], wn[4];

    // ---- prologue: A(0)->LDS buf0, W(0)->regs ----
    {
        float e0[8];
        loadA(e0, ak0);
        loadW(wc, 0);
        cvtStore(sm, e0, ak0);
    }
    soft_barrier();

    // ---- main loop: 1 soft barrier / step ----
    for (int ks = 0; ks < KS; ++ks) {
        const int cb = (ks & 1) ? BUF : 0;
        const int nb = cb ^ BUF;
        const bool hn = (ks + 1) < KS;

        // issue next-step global loads first (max in-flight time)
        float en[8];
        if (hn) {
            loadA(en, ((ks + 1) << 5) + ak0);
            loadW(wn, ks + 1);
        }

        // A fragments from LDS (ready since last barrier)
        bf16x8 ah[2], al[2];
        #pragma unroll
        for (int i = 0; i < 2; ++i) {
            const int ao = ((wrg + i) << 10) | (fkc << 8) | (fr << 4);
            ah[i] = *(const bf16x8*)(sm + cb + ao);
            al[i] = *(const bf16x8*)(sm + cb + PLANE + ao);
        }
        // 12 MFMA: hi*hi + hi*lo + lo*hi (A/B share k-map -> k-perm invariant)
        #pragma unroll
        for (int mi = 0; mi < 2; ++mi)
            #pragma unroll
            for (int ni = 0; ni < 2; ++ni) {
                acc[mi][ni] = __builtin_amdgcn_mfma_f32_16x16x32_bf16(ah[mi], wc[ni],     acc[mi][ni], 0, 0, 0);
                acc[mi][ni] = __builtin_amdgcn_mfma_f32_16x16x32_bf16(ah[mi], wc[2 + ni], acc[mi][ni], 0, 0, 0);
                acc[mi][ni] = __builtin_amdgcn_mfma_f32_16x16x32_bf16(al[mi], wc[ni],     acc[mi][ni], 0, 0, 0);
            }

        // convert + LDS store for next step (write-late)
        if (hn) cvtStore(sm + nb, en, ((ks + 1) << 5) + ak0);

        soft_barrier();
        if (hn) {
            #pragma unroll
            for (int i = 0; i < 4; ++i) wc[i] = wn[i];
        }
    }

    // ---- epilogue: bias, store, deterministic partial BN stats ----
    // C/D layout: col = lane&15, row = (lane>>4)*4 + reg
    float bv[2];
    #pragma unroll
    for (int ni = 0; ni < 2; ++ni)
        bv[ni] = bias[(size_t)c * Fout + o0 + wcol + (ni << 4) + fr];

    float p[2] = {}, q[2] = {};
    const int rsub = (lane >> 4) << 2;
    #pragma unroll
    for (int mi = 0; mi < 2; ++mi) {
        #pragma unroll
        for (int j = 0; j < 4; ++j) {
            const int row = b0 + wrow + (mi << 4) + rsub + j;
            float* op = Out + ((size_t)c * BB + row) * Fout + o0 + wcol;
            #pragma unroll
            for (int ni = 0; ni < 2; ++ni) {
                const float v = acc[mi][ni][j] + bv[ni];
                op[(ni << 4) + fr] = v;
                if (WRITE_STATS) { p[ni] += v; q[ni] += v * v; }
            }
        }
    }

    if (WRITE_STATS) {
        #pragma unroll
        for (int ni = 0; ni < 2; ++ni) {   // fold the 4 row-subgroups per column
            p[ni] += __shfl_xor(p[ni], 16); p[ni] += __shfl_xor(p[ni], 32);
            q[ni] += __shfl_xor(q[ni], 16); q[ni] += __shfl_xor(q[ni], 32);
        }
        float* redp = (float*)sm;           // [2][64] scratch (loop is done)
        float* redq = (float*)(sm + 512);
        if (lane < 16) {
            const int base = (wv >> 1) * 64 + wcol;
            #pragma unroll
            for (int ni = 0; ni < 2; ++ni) {
                redp[base + (ni << 4) + fr] = p[ni];
                redq[base + (ni << 4) + fr] = q[ni];
            }
        }
        __syncthreads();
        if (tid < 64) {
            const float sp = redp[tid] + redp[64 + tid];
            const float sq = redq[tid] + redq[64 + tid];
            const size_t o = ((size_t)c * Fout + o0 + tid) * NBT + btile;
            psumOut[o] = sp;
            psqOut[o]  = sq;
        }
    }
}

__global__ __launch_bounds__(256)
void label_kernel(float* __restrict__ out)
{
    const int i = blockIdx.x * 256 + threadIdx.x;
    out[i] = (float)(i >> 11);   // i / 2048
}

// ---------------------------------------------------------------------------
extern "C" void kernel_launch(void* const* d_in, const int* in_sizes, int n_in,
                              void* d_out, int out_size, void* d_ws, size_t ws_size,
                              hipStream_t stream)
{
    const float* x = (const float*)d_in[0];
    const float* W[5];  const float* bs[5];
    for (int l = 0; l < 5; ++l) { W[l] = (const float*)d_in[1 + 2 * l]; bs[l] = (const float*)d_in[2 + 2 * l]; }
    const float* g[4];  const float* be[4];
    for (int l = 0; l < 4; ++l) { g[l] = (const float*)d_in[11 + 2 * l]; be[l] = (const float*)d_in[12 + 2 * l]; }

    float* out     = (float*)d_out;
    float* gendata = out;                              // [C*BB, 512] — doubles as h1
    float* label   = out + (size_t)CCLS * BB * 512;

    float* ws  = (float*)d_ws;
    float* h2  = ws;                                   // 8,388,608 f (32MB)
    float* h3  = h2 + 8388608;                         // 4,194,304 f (16MB)
    float* h4  = h2;                                   // alias: h2 dead after G3
    float* ps1 = h3 + 4194304;                         // 16*512*32
    float* pq1 = ps1 + 262144;
    float* ps2 = pq1 + 262144;                         // 16*256*32
    float* pq2 = ps2 + 131072;
    float* ps3 = pq2 + 131072;                         // 16*128*32
    float* pq3 = ps3 + 65536;
    float* ps4 = pq3 + 65536;                          // 16*256*32
    float* pq4 = ps4 + 131072;
    char*  pack = (char*)(pq4 + 131072);               // 3072 x 8KB = 24MB

    const char* wpk1 = pack;
    const char* wpk2 = pack + (size_t)512  * 8192;
    const char* wpk3 = pack + (size_t)1536 * 8192;
    const char* wpk4 = pack + (size_t)1792 * 8192;
    const char* wpk5 = pack + (size_t)2048 * 8192;

    const dim3 blk(256);

    // one-time W pack -> fragment-major hi/lo bf16 64x32 tiles
    PackDesc pd;
    pd.src[0] = W[0]; pd.src[1] = W[1]; pd.src[2] = W[2]; pd.src[3] = W[3]; pd.src[4] = W[4];
    const int ot[5]    = {8, 4, 2, 4, 8};
    const int ksn[5]   = {4, 16, 8, 4, 8};
    const int kreal[5] = {100, 512, 256, 128, 256};
    const int beg[6]   = {0, 512, 1536, 1792, 2048, 3072};
    for (int i = 0; i < 5; ++i) { pd.ot[i] = ot[i]; pd.ksn[i] = ksn[i]; pd.kreal[i] = kreal[i]; }
    for (int i = 0; i < 6; ++i) pd.beg[i] = beg[i];
    pack_kernel<<<dim3(3072), blk, 0, stream>>>(pd, pack);

    // G1: x[K=100] -> h1(=gendata)[512], stats -> ps1
    gemm6_kernel<100, false, true><<<dim3(32, 8, CCLS), blk, 0, stream>>>(
        x, wpk1, bs[0], nullptr, nullptr, nullptr, nullptr,
        gendata, ps1, pq1, 512);

    // G2: bn1(h1)->relu -> h2[256], stats -> ps2
    gemm6_kernel<512, true, true><<<dim3(32, 4, CCLS), blk, 0, stream>>>(
        gendata, wpk2, bs[1], ps1, pq1, g[0], be[0],
        h2, ps2, pq2, 256);

    // G3: bn2(h2)->relu -> h3[128], stats -> ps3
    gemm6_kernel<256, true, true><<<dim3(32, 2, CCLS), blk, 0, stream>>>(
        h2, wpk3, bs[2], ps2, pq2, g[1], be[1],
        h3, ps3, pq3, 128);

    // G4: bn3(h3)->relu -> h4[256] (aliases h2), stats -> ps4
    gemm6_kernel<128, true, true><<<dim3(32, 4, CCLS), blk, 0, stream>>>(
        h3, wpk4, bs[3], ps3, pq3, g[2], be[2],
        h4, ps4, pq4, 256);

    // G5: bn4(h4)->relu -> gendata[512] (no stats)
    gemm6_kernel<256, true, false><<<dim3(32, 8, CCLS), blk, 0, stream>>>(
        h4, wpk5, bs[4], ps4, pq4, g[3], be[3],
        gendata, nullptr, nullptr, 512);

    label_kernel<<<dim3(CCLS * BB / 256), blk, 0, stream>>>(label);
}

// Round 8
// 158.749 us; speedup vs baseline: 1.3656x; 1.3656x over previous
//
#include <hip/hip_runtime.h>
#include <hip/hip_bf16.h>
#include <math.h>

#define CCLS 16
#define BB   2048

using bf16x8 = __attribute__((ext_vector_type(8))) short;
using short8 = __attribute__((ext_vector_type(8))) short;
using f32x4  = __attribute__((ext_vector_type(4))) float;

// fp32 -> (hi, lo) bf16 split (RNE; hi+lo reproduces ~24 mantissa bits)
__device__ __forceinline__ void split2(float e, short& hi, short& lo) {
    __hip_bfloat16 h = __float2bfloat16(e);
    hi = __builtin_bit_cast(short, h);
    lo = __builtin_bit_cast(short, __float2bfloat16(e - __bfloat162float(h)));
}

// LDS-visibility barrier that does NOT drain vmcnt: global loads stay in
// flight across it (compiler inserts counted vmcnt(N) before each use).
__device__ __forceinline__ void soft_barrier() {
    asm volatile("s_waitcnt lgkmcnt(0)" ::: "memory");
    __builtin_amdgcn_s_barrier();
    asm volatile("" ::: "memory");
}

// global -> LDS direct copy, 16B/lane; lds dest is wave-uniform base
__device__ __forceinline__ void gll16(const void* g, void* l) {
    __builtin_amdgcn_global_load_lds(
        (const __attribute__((address_space(1))) unsigned*)g,
        (__attribute__((address_space(3))) unsigned*)l, 16, 0, 0);
}

// Fragment-major layout for a 128-row x 32-k bf16 tile (8 KB/plane):
//   L(row, kchunk) = (row>>4)<<10 | kchunk<<8 | (row&15)<<4   (kchunk = k/8)
// A 16-lane frag read covers 256B contiguous -> conflict-free; linear order
// matches global_load_lds lane layout (both-sides-consistent, rule #21).

// ---------------------------------------------------------------------------
// One-time pack: x and W1..W5 -> [hi 8KB][lo 8KB] fragment-major 128x32 tiles.
// Tile order per source: (c, row-tile, ks). Zero-padded past kreal.
// ---------------------------------------------------------------------------
struct PackDesc {
    const float* src[6];
    int nrt[6];     // 128-row tiles per class
    int ksn[6];     // ceil(K/32)
    int kreal[6];
    int beg[7];
};

__global__ __launch_bounds__(256)
void pack_kernel(PackDesc d, char* __restrict__ base)
{
    const int bid = blockIdx.x;
    int s = 0;
    #pragma unroll
    for (int i = 0; i < 5; ++i) s += (bid >= d.beg[i + 1]);
    const int t    = bid - d.beg[s];
    const int ksn  = d.ksn[s], nrt = d.nrt[s], kreal = d.kreal[s];
    const int perc = nrt * ksn;
    const int c  = t / perc;
    const int r  = t - c * perc;
    const int rt = r / ksn;
    const int ks = r - rt * ksn;
    const float* src = d.src[s] + ((size_t)(c * nrt + rt) * 128) * kreal;
    char* dst = base + (size_t)bid * 16384;
    const int tid = threadIdx.x;

    #pragma unroll
    for (int it = 0; it < 2; ++it) {
        const int row = (tid >> 2) + (it << 6);
        const int cc  = tid & 3;
        const int q   = ((row >> 4) << 10) | (cc << 8) | ((row & 15) << 4);
        const int k0  = ks * 32 + cc * 8;
        const float* sp = src + (size_t)row * kreal + k0;
        float e[8];
        if (k0 + 8 <= kreal) {
            float4 v0 = *(const float4*)sp;
            float4 v1 = *(const float4*)(sp + 4);
            e[0]=v0.x; e[1]=v0.y; e[2]=v0.z; e[3]=v0.w;
            e[4]=v1.x; e[5]=v1.y; e[6]=v1.z; e[7]=v1.w;
        } else {
            #pragma unroll
            for (int j = 0; j < 8; ++j) e[j] = (k0 + j < kreal) ? sp[j] : 0.f;
        }
        short hv[8], lv[8];
        #pragma unroll
        for (int j = 0; j < 8; ++j) split2(e[j], hv[j], lv[j]);
        *(short8*)(dst + q)        = (short8){hv[0],hv[1],hv[2],hv[3],hv[4],hv[5],hv[6],hv[7]};
        *(short8*)(dst + 8192 + q) = (short8){lv[0],lv[1],lv[2],lv[3],lv[4],lv[5],lv[6],lv[7]};
    }
}

// ---------------------------------------------------------------------------
// MFMA GEMM, fp32 via bf16 hi/lo 3-product emulation.
// PREPACK (G1): A and W tiles both staged LDS-direct via global_load_lds
//   (m97 structure; __syncthreads drains per step). Zero loop VALU.
// else: A (fp32) reg-staged 2-DEEP (A(ks+2) issued at step ks, BN+ReLU+cvt
//   at ks+1, consumed at ks+2) -> full-step latency cover; explicit ping-pong
//   named registers (no runtime-indexed arrays). W fragments global->VGPR,
//   register-dbuf one step ahead. One soft barrier per step (vmcnt alive).
// Tile BM x 128 x 32; 4 waves 2x2, each (BM/2)x64 via (BM/32)x4 frags.
// ---------------------------------------------------------------------------
template<int BM, int K, bool PREPACK, bool FUSE_BN, bool WRITE_STATS>
__global__ __launch_bounds__(256, 2)
void gemm7_kernel(const float* __restrict__ A, const char* __restrict__ Apk,
                  const char* __restrict__ Wpk, const float* __restrict__ bias,
                  const float* __restrict__ psumIn, const float* __restrict__ psqIn,
                  const float* __restrict__ gIn, const float* __restrict__ beIn,
                  float* __restrict__ Out,
                  float* __restrict__ psumOut, float* __restrict__ psqOut,
                  const int Fout, const int nbtIn)
{
    constexpr int KS    = (K + 31) / 32;
    constexpr int PLANE = BM * 64;                      // bytes per hi/lo plane
    constexpr int BUFSZ = PREPACK ? 32768 : 2 * PLANE;  // A(+W if prepack)
    static_assert(PREPACK || (K % 32 == 0), "non-prepack K must be mult of 32");
    static_assert(PREPACK || (KS % 2 == 0) || (KS == 1), "ping-pong needs even KS");

    __shared__ __align__(16) char sm[2 * BUFSZ + (FUSE_BN ? 8 * K : 16)];
    float* scs = (float*)(sm + 2 * BUFSZ);
    float* shs = scs + (FUSE_BN ? K : 0);

    const int tid   = threadIdx.x;
    const int btile = blockIdx.x, otile = blockIdx.y, c = blockIdx.z;

    // ---- folded combine: BN scale/shift for this layer's INPUT features ----
    if (FUSE_BN) {
        for (int f = tid; f < K; f += 256) {
            const float* ps = psumIn + ((size_t)c * K + f) * nbtIn;
            const float* pq = psqIn  + ((size_t)c * K + f) * nbtIn;
            float s = 0.f, q = 0.f;
            for (int t = 0; t < nbtIn; t += 4) {
                float4 a4 = *(const float4*)(ps + t);
                float4 b4 = *(const float4*)(pq + t);
                s += (a4.x + a4.y) + (a4.z + a4.w);
                q += (b4.x + b4.y) + (b4.z + b4.w);
            }
            const float mean = s * (1.f / BB);
            const float var  = q * (1.f / BB) - mean * mean;
            const float rstd = rsqrtf(var + 1e-5f);
            const float scv  = gIn[(size_t)c * K + f] * rstd;
            scs[f] = scv;
            shs[f] = fmaf(-mean, scv, beIn[(size_t)c * K + f]);
        }
        __syncthreads();
    }

    const int b0 = btile * BM, o0 = otile * 128;
    const int OT = Fout >> 7;
    const char* wbase = Wpk + (size_t)((c * OT + otile) * KS) * 16384;
    const char* abase = PREPACK ? (Apk + (size_t)((c * gridDim.x + btile) * KS) * 16384) : nullptr;

    // fragment map: 4 waves 2x2
    const int lane = tid & 63, wv = tid >> 6;
    const int fr = lane & 15, fkc = lane >> 4;
    const int wrow = (BM == 128) ? ((wv >> 1) << 6) : ((wv >> 1) << 5);
    const int wcol = (wv & 1) << 6;
    const int wrg = wrow >> 4, wcg = wcol >> 4;
    constexpr int MI = BM / 32;

    f32x4 acc[MI][4];
    #pragma unroll
    for (int mi = 0; mi < MI; ++mi)
        #pragma unroll
        for (int ni = 0; ni < 4; ++ni)
            acc[mi][ni] = (f32x4){0.f, 0.f, 0.f, 0.f};

    if constexpr (PREPACK) {
        // ================= m97-style loop: LDS-direct A+W staging ==========
        auto stageTile = [&](int nb, int ks) {
            const char* at = abase + (size_t)ks * 16384;
            const char* wt = wbase + (size_t)ks * 16384;
            char* dst = sm + nb;
            #pragma unroll
            for (int i = 0; i < 4; ++i) {
                const int rg = ((wv << 2) + i) << 10;
                gll16(at + rg + (lane << 4), dst + rg);
                gll16(wt + rg + (lane << 4), dst + 16384 + rg);
            }
        };
        stageTile(0, 0);
        __syncthreads();
        for (int ks = 0; ks < KS; ++ks) {
            const int cb = (ks & 1) ? BUFSZ : 0;
            if (ks + 1 < KS) stageTile(cb ^ BUFSZ, ks + 1);
            bf16x8 ah[MI], al[MI], wh[4], wl[4];
            #pragma unroll
            for (int i = 0; i < 4; ++i) {
                const int wo = ((wcg + i) << 10) | (fkc << 8) | (fr << 4);
                wh[i] = *(const bf16x8*)(sm + cb + 16384 + wo);
                wl[i] = *(const bf16x8*)(sm + cb + 24576 + wo);
            }
            #pragma unroll
            for (int i = 0; i < MI; ++i) {
                const int ao = ((wrg + i) << 10) | (fkc << 8) | (fr << 4);
                ah[i] = *(const bf16x8*)(sm + cb + ao);
                al[i] = *(const bf16x8*)(sm + cb + 8192 + ao);
            }
            #pragma unroll
            for (int mi = 0; mi < MI; ++mi)
                #pragma unroll
                for (int ni = 0; ni < 4; ++ni) {
                    acc[mi][ni] = __builtin_amdgcn_mfma_f32_16x16x32_bf16(ah[mi], wh[ni], acc[mi][ni], 0, 0, 0);
                    acc[mi][ni] = __builtin_amdgcn_mfma_f32_16x16x32_bf16(ah[mi], wl[ni], acc[mi][ni], 0, 0, 0);
                    acc[mi][ni] = __builtin_amdgcn_mfma_f32_16x16x32_bf16(al[mi], wh[ni], acc[mi][ni], 0, 0, 0);
                }
            __syncthreads();   // drains vmcnt: staged tile ready
        }
    } else {
        // ============== reg-staged loop: 2-deep A, W-dbuf, soft barrier ====
        constexpr int NV = BM / 32;    // float4 A-loads per thread per step
        const int arow = (BM == 128) ? (tid >> 1) : (tid >> 2);
        const int asub = (BM == 128) ? (tid & 1)  : (tid & 3);
        const int ak0  = (BM == 128) ? (asub << 4) : (asub << 3);
        const int kch  = (BM == 128) ? (asub << 1) : asub;
        const int awr  = ((arow >> 4) << 10) | (kch << 8) | ((arow & 15) << 4);
        const float* Arow = A + ((size_t)c * BB + b0 + arow) * K;

        auto loadA = [&](float4 (&av)[NV], int gk0) {
            #pragma unroll
            for (int i = 0; i < NV; ++i)
                av[i] = *(const float4*)(Arow + gk0 + (i << 2));
        };
        auto loadW = [&](bf16x8 (&w)[8], int ks) {
            const char* wt = wbase + (size_t)ks * 16384;
            #pragma unroll
            for (int i = 0; i < 4; ++i) {
                const int wo = ((wcg + i) << 10) | (fkc << 8) | (fr << 4);
                w[i]     = *(const bf16x8*)(wt + wo);
                w[4 + i] = *(const bf16x8*)(wt + 8192 + wo);
            }
        };
        auto cvtStore = [&](char* dstbase, const float4 (&a)[NV], int gk0) {
            float e[NV * 4];
            #pragma unroll
            for (int i = 0; i < NV; ++i) {
                e[i*4+0] = a[i].x; e[i*4+1] = a[i].y; e[i*4+2] = a[i].z; e[i*4+3] = a[i].w;
            }
            if constexpr (FUSE_BN) {
                #pragma unroll
                for (int i = 0; i < NV; ++i) {
                    const float4 sc = *(const float4*)(scs + gk0 + (i << 2));
                    const float4 sh = *(const float4*)(shs + gk0 + (i << 2));
                    e[i*4+0] = fmaxf(0.f, fmaf(e[i*4+0], sc.x, sh.x));
                    e[i*4+1] = fmaxf(0.f, fmaf(e[i*4+1], sc.y, sh.y));
                    e[i*4+2] = fmaxf(0.f, fmaf(e[i*4+2], sc.z, sh.z));
                    e[i*4+3] = fmaxf(0.f, fmaf(e[i*4+3], sc.w, sh.w));
                }
            }
            short h[NV*4], l[NV*4];
            #pragma unroll
            for (int j = 0; j < NV*4; ++j) split2(e[j], h[j], l[j]);
            *(short8*)(dstbase + awr)         = (short8){h[0],h[1],h[2],h[3],h[4],h[5],h[6],h[7]};
            *(short8*)(dstbase + PLANE + awr) = (short8){l[0],l[1],l[2],l[3],l[4],l[5],l[6],l[7]};
            if constexpr (NV == 4) {
                *(short8*)(dstbase + awr + 256)         = (short8){h[8],h[9],h[10],h[11],h[12],h[13],h[14],h[15]};
                *(short8*)(dstbase + PLANE + awr + 256) = (short8){l[8],l[9],l[10],l[11],l[12],l[13],l[14],l[15]};
            }
        };

        bf16x8 wcA[8], wcB[8];
        float4 avP[NV], avQ[NV];

        // one full step body; names passed explicitly (rule #20: static SSA)
        auto step = [&](int ks, char* cbp, char* nbp,
                        float4 (&avUse)[NV], float4 (&avLoad)[NV],
                        bf16x8 (&wUse)[8], bf16x8 (&wLoad)[8]) {
            const bool hn  = (ks + 1) < KS;
            const bool hn2 = (ks + 2) < KS;
            if (hn2) loadA(avLoad, ((ks + 2) << 5) + ak0);   // 2 steps ahead
            if (hn)  loadW(wLoad, ks + 1);                    // 1 step ahead
            bf16x8 ah[MI], al[MI];
            #pragma unroll
            for (int i = 0; i < MI; ++i) {
                const int ao = ((wrg + i) << 10) | (fkc << 8) | (fr << 4);
                ah[i] = *(const bf16x8*)(cbp + ao);
                al[i] = *(const bf16x8*)(cbp + PLANE + ao);
            }
            #pragma unroll
            for (int mi = 0; mi < MI; ++mi)
                #pragma unroll
                for (int ni = 0; ni < 4; ++ni) {
                    acc[mi][ni] = __builtin_amdgcn_mfma_f32_16x16x32_bf16(ah[mi], wUse[ni],     acc[mi][ni], 0, 0, 0);
                    acc[mi][ni] = __builtin_amdgcn_mfma_f32_16x16x32_bf16(ah[mi], wUse[4 + ni], acc[mi][ni], 0, 0, 0);
                    acc[mi][ni] = __builtin_amdgcn_mfma_f32_16x16x32_bf16(al[mi], wUse[ni],     acc[mi][ni], 0, 0, 0);
                }
            if (hn) cvtStore(nbp, avUse, ((ks + 1) << 5) + ak0);  // data 1 step old
            soft_barrier();
        };

        // prologue: A(0) direct, W(0), A(1) issued before the cvt stall
        {
            float4 av0[NV];
            loadA(av0, ak0);
            loadW(wcA, 0);
            if (KS > 1) loadA(avP, 32 + ak0);
            cvtStore(sm, av0, ak0);
        }
        soft_barrier();

        for (int ks = 0; ks < KS; ks += 2) {
            step(ks,     sm,         sm + BUFSZ, avP, avQ, wcA, wcB);
            step(ks + 1, sm + BUFSZ, sm,         avQ, avP, wcB, wcA);
        }
    }

    // ---- epilogue: bias, store, deterministic partial BN stats ----
    // C/D layout: col = lane&15, row = (lane>>4)*4 + reg
    float bv[4];
    #pragma unroll
    for (int ni = 0; ni < 4; ++ni)
        bv[ni] = bias[(size_t)c * Fout + o0 + wcol + (ni << 4) + fr];

    float p[4] = {}, q[4] = {};
    const int rsub = (lane >> 4) << 2;
    #pragma unroll
    for (int mi = 0; mi < MI; ++mi) {
        #pragma unroll
        for (int j = 0; j < 4; ++j) {
            const int row = b0 + wrow + (mi << 4) + rsub + j;
            float* op = Out + ((size_t)c * BB + row) * Fout + o0 + wcol;
            #pragma unroll
            for (int ni = 0; ni < 4; ++ni) {
                const float v = acc[mi][ni][j] + bv[ni];
                op[(ni << 4) + fr] = v;
                if (WRITE_STATS) { p[ni] += v; q[ni] += v * v; }
            }
        }
    }

    if (WRITE_STATS) {
        #pragma unroll
        for (int ni = 0; ni < 4; ++ni) {
            p[ni] += __shfl_xor(p[ni], 16); p[ni] += __shfl_xor(p[ni], 32);
            q[ni] += __shfl_xor(q[ni], 16); q[ni] += __shfl_xor(q[ni], 32);
        }
        __syncthreads();                   // loop done; reuse sm as scratch
        float* redp = (float*)sm;          // [2][128]
        float* redq = (float*)(sm + 1024);
        if (lane < 16) {
            const int base = (wv >> 1) * 128 + wcol;
            #pragma unroll
            for (int ni = 0; ni < 4; ++ni) {
                redp[base + (ni << 4) + fr] = p[ni];
                redq[base + (ni << 4) + fr] = q[ni];
            }
        }
        __syncthreads();
        if (tid < 128) {
            const float sp = redp[tid] + redp[128 + tid];
            const float sq = redq[tid] + redq[128 + tid];
            const size_t o = ((size_t)c * Fout + o0 + tid) * gridDim.x + btile;
            psumOut[o] = sp;
            psqOut[o]  = sq;
        }
    }
}

__global__ __launch_bounds__(256)
void label_kernel(float* __restrict__ out)
{
    const int i = blockIdx.x * 256 + threadIdx.x;
    out[i] = (float)(i >> 11);   // i / 2048
}

// ---------------------------------------------------------------------------
extern "C" void kernel_launch(void* const* d_in, const int* in_sizes, int n_in,
                              void* d_out, int out_size, void* d_ws, size_t ws_size,
                              hipStream_t stream)
{
    const float* x = (const float*)d_in[0];
    const float* W[5];  const float* bs[5];
    for (int l = 0; l < 5; ++l) { W[l] = (const float*)d_in[1 + 2 * l]; bs[l] = (const float*)d_in[2 + 2 * l]; }
    const float* g[4];  const float* be[4];
    for (int l = 0; l < 4; ++l) { g[l] = (const float*)d_in[11 + 2 * l]; be[l] = (const float*)d_in[12 + 2 * l]; }

    float* out     = (float*)d_out;
    float* gendata = out;                              // [C*BB, 512] — doubles as h1
    float* label   = out + (size_t)CCLS * BB * 512;

    float* ws  = (float*)d_ws;
    float* h2  = ws;                                   // 8,388,608 f (32MB)
    float* h3  = h2 + 8388608;                         // 4,194,304 f (16MB)
    float* h4  = h2;                                   // alias: h2 dead after G3
    float* ps1 = h3 + 4194304;                         // 16*512*16
    float* pq1 = ps1 + 131072;
    float* ps2 = pq1 + 131072;                         // 16*256*16
    float* pq2 = ps2 + 65536;
    float* ps3 = pq2 + 65536;                          // 16*128*32
    float* pq3 = ps3 + 65536;
    float* ps4 = pq3 + 65536;                          // 16*256*16
    float* pq4 = ps4 + 65536;
    char*  pack = (char*)(pq4 + 65536);                // 2560 x 16KB = 40MB

    const char* xpk  = pack;
    const char* wpk1 = pack + (size_t)1024 * 16384;
    const char* wpk2 = pack + (size_t)1280 * 16384;
    const char* wpk3 = pack + (size_t)1792 * 16384;
    const char* wpk4 = pack + (size_t)1920 * 16384;
    const char* wpk5 = pack + (size_t)2048 * 16384;

    const dim3 blk(256);

    // one-time pack: x + W1..W5 -> fragment-major hi/lo bf16 128x32 tiles
    PackDesc pd;
    pd.src[0] = x;    pd.src[1] = W[0]; pd.src[2] = W[1];
    pd.src[3] = W[2]; pd.src[4] = W[3]; pd.src[5] = W[4];
    const int nrt[6]   = {16, 4, 2, 1, 2, 4};
    const int ksn[6]   = {4, 4, 16, 8, 4, 8};
    const int kreal[6] = {100, 100, 512, 256, 128, 256};
    const int beg[7]   = {0, 1024, 1280, 1792, 1920, 2048, 2560};
    for (int i = 0; i < 6; ++i) { pd.nrt[i] = nrt[i]; pd.ksn[i] = ksn[i]; pd.kreal[i] = kreal[i]; }
    for (int i = 0; i < 7; ++i) pd.beg[i] = beg[i];
    pack_kernel<<<dim3(2560), blk, 0, stream>>>(pd, pack);

    // G1: x[K=100->128] -> h1(=gendata)[512], stats (PREPACK m97-style)
    gemm7_kernel<128, 128, true, false, true><<<dim3(16, 4, CCLS), blk, 0, stream>>>(
        nullptr, xpk, wpk1, bs[0], nullptr, nullptr, nullptr, nullptr,
        gendata, ps1, pq1, 512, 0);

    // G2: bn1(h1)->relu -> h2[256], stats
    gemm7_kernel<128, 512, false, true, true><<<dim3(16, 2, CCLS), blk, 0, stream>>>(
        gendata, nullptr, wpk2, bs[1], ps1, pq1, g[0], be[0],
        h2, ps2, pq2, 256, 16);

    // G3: bn2(h2)->relu -> h3[128], stats (BM=64)
    gemm7_kernel<64, 256, false, true, true><<<dim3(32, 1, CCLS), blk, 0, stream>>>(
        h2, nullptr, wpk3, bs[2], ps2, pq2, g[1], be[1],
        h3, ps3, pq3, 128, 16);

    // G4: bn3(h3)->relu -> h4[256] (aliases h2), stats
    gemm7_kernel<128, 128, false, true, true><<<dim3(16, 2, CCLS), blk, 0, stream>>>(
        h3, nullptr, wpk4, bs[3], ps3, pq3, g[2], be[2],
        h4, ps4, pq4, 256, 32);

    // G5: bn4(h4)->relu -> gendata[512] (no stats)
    gemm7_kernel<128, 256, false, true, false><<<dim3(16, 4, CCLS), blk, 0, stream>>>(
        h4, nullptr, wpk5, bs[4], ps4, pq4, g[3], be[3],
        gendata, nullptr, nullptr, 512, 16);

    label_kernel<<<dim3(CCLS * BB / 256), blk, 0, stream>>>(label);
}